// Round 2
// baseline (208.050 us; speedup 1.0000x reference)
//
#include <hip/hip_runtime.h>
#include <hip/hip_bf16.h>
#include <string.h>

#define Bsz 2
#define Tsz 2048
#define Dsz 1024
#define NHsz 16
#define Msz (Bsz*Tsz)  // 4096 rows total

typedef unsigned short bfu;  // bf16 bit pattern
typedef __attribute__((ext_vector_type(8))) short short8;   // MFMA A/B frag: 8 bf16
typedef __attribute__((ext_vector_type(4))) short short4v;
typedef __attribute__((ext_vector_type(4))) float floatx4;  // MFMA C/D frag

__device__ __forceinline__ bfu f2bf(float f) {
  unsigned int u = __builtin_bit_cast(unsigned int, f);
  u += 0x7fffu + ((u >> 16) & 1u);
  return (bfu)(u >> 16);
}

__device__ __forceinline__ short4v pack4bf(float a, float b, float c_, float d) {
  // v_cvt_pk_bf16_f32: 2 ops for 4 values
  __hip_bfloat162 h01 = __float22bfloat162_rn(make_float2(a, b));
  __hip_bfloat162 h23 = __float22bfloat162_rn(make_float2(c_, d));
  uint2 uu;
  memcpy(&uu.x, &h01, 4);
  memcpy(&uu.y, &h23, 4);
  return __builtin_bit_cast(short4v, uu);
}

__device__ __forceinline__ short8 pack8bf(float4 a, float4 b) {
  __hip_bfloat162 h0 = __float22bfloat162_rn(make_float2(a.x, a.y));
  __hip_bfloat162 h1 = __float22bfloat162_rn(make_float2(a.z, a.w));
  __hip_bfloat162 h2 = __float22bfloat162_rn(make_float2(b.x, b.y));
  __hip_bfloat162 h3 = __float22bfloat162_rn(make_float2(b.z, b.w));
  uint4 u;
  memcpy(&u.x, &h0, 4); memcpy(&u.y, &h1, 4);
  memcpy(&u.z, &h2, 4); memcpy(&u.w, &h3, 4);
  return __builtin_bit_cast(short8, u);
}

__device__ __forceinline__ void async16(const void* g, void* l) {
  void* gnc = (void*)g;
  __builtin_amdgcn_global_load_lds((__attribute__((address_space(1))) void*)gnc,
                                   (__attribute__((address_space(3))) void*)l,
                                   16, 0, 0);
}

// ---------------- W (KxN fp32) -> WT (NxK bf16), z = 4 weights ----------------
// z==0 (Wq) pre-scaled by log2e/sqrt(DH) so the GEMM epilogue needs no scale.
__global__ __launch_bounds__(256) void transpose_w(const float* __restrict__ W0, const float* __restrict__ W1,
                                                   const float* __restrict__ W2, const float* __restrict__ W3,
                                                   bfu* __restrict__ wt) {
  __shared__ float tile[32][33];
  const float* W = blockIdx.z == 0 ? W0 : blockIdx.z == 1 ? W1 : blockIdx.z == 2 ? W2 : W3;
  const float s = (blockIdx.z == 0) ? 0.18033688011112042f : 1.0f;  // 0.125*log2(e)
  bfu* WT = wt + (size_t)blockIdx.z * Dsz * Dsz;
  int tx = threadIdx.x, ty = threadIdx.y;           // 32 x 8
  int kb = blockIdx.y * 32, nb = blockIdx.x * 32;
#pragma unroll
  for (int i = 0; i < 4; ++i)
    tile[ty + i*8][tx] = W[(size_t)(kb + ty + i*8) * Dsz + nb + tx];
  __syncthreads();
#pragma unroll
  for (int i = 0; i < 4; ++i)
    WT[(size_t)(nb + ty + i*8) * Dsz + kb + tx] = f2bf(tile[tx][ty + i*8] * s);
}

// ---------------- 128xNT bf16 MFMA GEMM: C = A(MxK) * BT(NxK)^T ----------------
// AF32: A fp32, converted in-regs (software-pipelined).
// z==2 (NT=128, bf16 out): V written transposed VT[b][h][d][t] via LDS-coalesced epilogue.
template <bool F32OUT, bool AF32, int NT>
__global__ __launch_bounds__(256) void gemm128(const void* __restrict__ Ain, const bfu* __restrict__ Bt0,
                                               void* __restrict__ C0, int K, int N,
                                               size_t strideB, size_t strideC) {
  constexpr int NJ = NT / 32;                       // n-frags per wave
  const int tid = threadIdx.x, wave = tid >> 6, lane = tid & 63;
  const int g = lane >> 4, c = lane & 15;
  const int m0 = blockIdx.y * 128, n0 = blockIdx.x * NT;
  const bfu* Bt = Bt0 + strideB * blockIdx.z;
  __shared__ bfu smem[4096 + NT * 32];              // As | Bs (also VT-transpose buf)
  bfu* As = smem;
  bfu* Bs = smem + 4096;
  floatx4 acc[4][NJ] = {};
  const int srow = lane >> 2, scol = (lane & 3) * 8;
  const bfu* gB = Bt + (size_t)(n0 + srow) * K + scol;
  const int wm = (wave >> 1) * 64, wn = (wave & 1) * (NT / 2);

  short8 areg[2];
  if (AF32) {   // preload k0=0 A-chunks as fp32, convert in regs
#pragma unroll
    for (int cc = 0; cc < 2; ++cc) {
      const float* pa = (const float*)Ain +
          (size_t)(m0 + (wave*2 + cc)*16 + srow) * K + scol;
      areg[cc] = pack8bf(((const float4*)pa)[0], ((const float4*)pa)[1]);
    }
  }
  const bfu* gA = AF32 ? nullptr : (const bfu*)Ain + (size_t)(m0 + srow) * K + scol;

  for (int k0 = 0; k0 < K; k0 += 32) {
    __syncthreads();               // prior reads done before overwrite
#pragma unroll
    for (int cc = 0; cc < 2; ++cc) {
      const int chunk = wave * 2 + cc;
      if (AF32) *(short8*)&As[chunk * 512 + lane * 8] = areg[cc];
      else      async16(gA + (size_t)chunk * 16 * K + k0, &As[chunk * 512]);
    }
#pragma unroll
    for (int cc = 0; cc < NT/64; ++cc) {
      const int chunk = wave * (NT/64) + cc;
      async16(gB + (size_t)chunk * 16 * K + k0, &Bs[chunk * 512]);
    }
    __syncthreads();
    if (AF32 && k0 + 32 < K) {     // prefetch next A slab (overlaps with MFMA below)
#pragma unroll
      for (int cc = 0; cc < 2; ++cc) {
        const float* pa = (const float*)Ain +
            (size_t)(m0 + (wave*2 + cc)*16 + srow) * K + (k0 + 32) + scol;
        areg[cc] = pack8bf(((const float4*)pa)[0], ((const float4*)pa)[1]);
      }
    }
    short8 afr[4], bfr[NJ];
#pragma unroll
    for (int t = 0; t < 4; ++t) afr[t] = *(const short8*)&As[(wm + t*16 + c) * 32 + g * 8];
#pragma unroll
    for (int t = 0; t < NJ; ++t) bfr[t] = *(const short8*)&Bs[(wn + t*16 + c) * 32 + g * 8];
#pragma unroll
    for (int i = 0; i < 4; ++i)
#pragma unroll
      for (int j = 0; j < NJ; ++j)
        acc[i][j] = __builtin_amdgcn_mfma_f32_16x16x32_bf16(afr[i], bfr[j], acc[i][j], 0, 0, 0);
  }

  const bool vtrans = (!F32OUT) && (NT == 128) && (blockIdx.z == 2);
  if (vtrans) {
    // LDS-coalesced transpose: 2 passes of 64 n-cols (= one head each) x 128 m.
    bfu* vtp = (bfu*)C0 + (size_t)2 * strideC;
#pragma unroll
    for (int p = 0; p < 2; ++p) {
      __syncthreads();             // As/Bs reads (or prior pass stores) complete
      if ((wave & 1) == p) {       // waves holding n-cols [p*64, p*64+64)
#pragma unroll
        for (int i = 0; i < 4; ++i)
#pragma unroll
          for (int j = 0; j < NJ; ++j) {
            const int nl = j*16 + c;                      // 0..63 within pass
            const int mg = ((wm + i*16) >> 3) + (g >> 1); // m-granule of 8
            const int phys = nl * 128 + ((mg ^ (nl & 15)) << 3) + ((g & 1) << 2);
            *(short4v*)&smem[phys] = pack4bf(acc[i][j][0], acc[i][j][1],
                                             acc[i][j][2], acc[i][j][3]);
          }
      }
      __syncthreads();
      const int h_ = (n0 + p * 64) >> 6;
      bfu* dst = vtp + ((size_t)((m0 >> 11) * 16 + h_) * 64) * Tsz + (m0 & 2047);
#pragma unroll
      for (int s = 0; s < 4; ++s) {
        const int nl = s * 16 + (tid >> 4);
        const int me = (tid & 15) << 3;
        const int phys = nl * 128 + (((me >> 3) ^ (nl & 15)) << 3);
        *(short8*)&dst[(size_t)nl * Tsz + me] = *(const short8*)&smem[phys];
      }
    }
    return;
  }

#pragma unroll
  for (int i = 0; i < 4; ++i) {
#pragma unroll
    for (int j = 0; j < NJ; ++j) {
      const int m = m0 + wm + i*16 + g*4;
      const int n = n0 + wn + j*16 + c;
#pragma unroll
      for (int r = 0; r < 4; ++r) {
        float v = acc[i][j][r];
        if (F32OUT) ((float*)C0)[(size_t)(m + r) * N + n] = v;
        else        ((bfu*)C0)[strideC * blockIdx.z + (size_t)(m + r) * N + n] = f2bf(v);
      }
    }
  }
}

// ---------------- causal flash attention (S^T formulation, v2) ----------------
// Q,K natural [b*T+t][h*64+d]; V transposed at qkv+2*M*D as VT[b][h][d][t].
// Q pre-scaled by log2e/sqrt(DH) (folded into Wq).
// v2 structure:
//  * fused q-tile pair {jA, 31-jA} in ONE kt sweep: kf/vf LDS reads shared by
//    both tiles' MFMAs; staging done once; per-block work = 17 tile-comps always.
//  * PV via v_mfma_f32_16x16x16_bf16: its A-frag key layout ((l>>4)*4+j) equals
//    the 16x16 C-layout of QK^T -> P stays IN REGISTERS (cvt_pk pack), no Ps LDS.
//  * K/V double-buffered (2x32KB) with counted s_waitcnt vmcnt(8) + raw
//    s_barrier (clobber-sandwiched): staging latency hidden, no vmcnt(0) drain.
//  * XCD swizzle: wg->XCD is i%8; give each XCD 4 heads so K/V (2MB) sits in
//    its 4MB L2.  * defer-max rescale (skip O-rescale when max grew <= 8 log2).
__global__ __launch_bounds__(256, 2) void attn_kernel(const bfu* __restrict__ qkv,
                                                      bfu* __restrict__ obuf) {
  const int tid = threadIdx.x, wave = tid >> 6, lane = tid & 63;
  const int g = (lane >> 4) & 3, c = lane & 15, c7 = c & 7;

  // XCD-aware remap (bijective): flat -> (xcd = flat&7, k = flat>>3)
  const int flat = (int)blockIdx.y * 16 + (int)blockIdx.x;
  const int bh = (flat & 7) * 4 + ((flat >> 3) >> 4);   // 4 consecutive bh per XCD
  const int jA = (flat >> 3) & 15, jB = 31 - jA;
  const int b = bh >> 4, h = bh & 15;
  const int ktmA = jA >> 1;            // A needs kt 0..ktmA
  const int ktm = 15 - ktmA;           // = ktmB >= 8; loop bound

  const size_t hb = (size_t)b * Tsz * Dsz + h * 64;
  const bfu* Qp = qkv + hb;
  const bfu* Kp = qkv + (size_t)Msz * Dsz + hb;
  const bfu* Vt = qkv + (size_t)2 * Msz * Dsz + (size_t)bh * 64 * Tsz;

  __shared__ bfu Ks[2][128 * 64];      // [key][d], d-octets XOR (key&7)
  __shared__ bfu Vs[2][64 * 128];      // [d][key], key-octets XOR (d&15)

  const int qwA = jA * 64 + wave * 16, qwB = jB * 64 + wave * 16;

  short8 bqA[2], bqB[2];               // Q B-frags: n=q=qw+c, k=d
#pragma unroll
  for (int kk = 0; kk < 2; ++kk) {
    bqA[kk] = *(const short8*)(Qp + (size_t)(qwA + c) * Dsz + kk * 32 + g * 8);
    bqB[kk] = *(const short8*)(Qp + (size_t)(qwB + c) * Dsz + kk * 32 + g * 8);
  }

  // staging pointers (advance per staged tile)
  const int kst_row = lane >> 3;                    // K: 8 lanes/key-row
  const int kst_off = ((lane & 7) ^ kst_row) << 3;
  const int vst_row = lane >> 4;                    // V: 16 lanes/d-row
  const bfu* kpp[4]; const bfu* vpp[4];
#pragma unroll
  for (int cc = 0; cc < 4; ++cc) {
    const int ch = wave * 4 + cc;
    kpp[cc] = Kp + (size_t)(ch * 8 + kst_row) * Dsz + kst_off;
    const int drow = ch * 4 + vst_row;
    vpp[cc] = Vt + (size_t)drow * Tsz + (((lane & 15) ^ (drow & 15)) << 3);
  }

  floatx4 accA[4] = {}, accB[4] = {};  // O: rows q=4g+r, cols d=nd*16+c
  float miA = -3.0e38f, liA = 0.0f, miB = -3.0e38f, liB = 0.0f;

  const floatx4 z4 = {0.0f, 0.0f, 0.0f, 0.0f};

  // online softmax on one tile's S^T frags; packs P into K=16 A-frags (regs)
  auto smax = [&](floatx4* st, float& mi, float& li, floatx4* acc,
                  short4v* pa, int qw, int diag, int ktt) {
    if (diag) {                        // causal mask (diagonal tile only)
#pragma unroll
      for (int mk = 0; mk < 8; ++mk) {
        const int keyb = ktt * 128 + mk * 16 + g * 4;
#pragma unroll
        for (int r = 0; r < 4; ++r)
          if (keyb + r > qw + c) st[mk][r] = -1.0e38f;
      }
    }
    float mloc = -3.0e38f;
#pragma unroll
    for (int mk = 0; mk < 8; ++mk)
      mloc = fmaxf(mloc, fmaxf(fmaxf(st[mk][0], st[mk][1]),
                               fmaxf(st[mk][2], st[mk][3])));
    mloc = fmaxf(mloc, __shfl_xor(mloc, 16));
    mloc = fmaxf(mloc, __shfl_xor(mloc, 32));
    const float mcand = fmaxf(mi, mloc);
    const bool resc = !__all(mcand - mi <= 8.0f);   // defer-max (T13)
    const float mnew = resc ? mcand : mi;
    float sum = 0.0f;
#pragma unroll
    for (int mk = 0; mk < 8; ++mk) {
      const float p0 = exp2f(st[mk][0] - mnew);
      const float p1 = exp2f(st[mk][1] - mnew);
      const float p2 = exp2f(st[mk][2] - mnew);
      const float p3 = exp2f(st[mk][3] - mnew);
      sum += (p0 + p1) + (p2 + p3);
      pa[mk] = pack4bf(p0, p1, p2, p3);             // K=16 A-frag, in regs
    }
    sum += __shfl_xor(sum, 16);
    sum += __shfl_xor(sum, 32);
    if (resc) {
      const float alpha = exp2f(mi - mnew);
      li = li * alpha + sum;
      mi = mnew;
      float al[4];
#pragma unroll
      for (int r = 0; r < 4; ++r) al[r] = __shfl(alpha, (lane & 48) | (g * 4 + r));
#pragma unroll
      for (int nd = 0; nd < 4; ++nd)
#pragma unroll
        for (int r = 0; r < 4; ++r) acc[nd][r] *= al[r];
    } else {
      li += sum;
    }
  };

  // prologue: stage kt=0 into buf 0
#pragma unroll
  for (int cc = 0; cc < 4; ++cc) {
    const int ch = wave * 4 + cc;
    async16(kpp[cc], &Ks[0][ch * 512]);
    async16(vpp[cc], &Vs[0][ch * 512]);
    kpp[cc] += (size_t)128 * Dsz;
    vpp[cc] += 128;
  }

  for (int kt = 0; kt <= ktm; ++kt) {
    const int cur = kt & 1;
    if (kt < ktm) {                    // prefetch kt+1 into other buffer
#pragma unroll
      for (int cc = 0; cc < 4; ++cc) {
        const int ch = wave * 4 + cc;
        async16(kpp[cc], &Ks[cur ^ 1][ch * 512]);
        async16(vpp[cc], &Vs[cur ^ 1][ch * 512]);
        kpp[cc] += (size_t)128 * Dsz;
        vpp[cc] += 128;
      }
      asm volatile("s_waitcnt vmcnt(8)" ::: "memory");  // cur's 8 landed
    } else {
      asm volatile("s_waitcnt vmcnt(0)" ::: "memory");
    }
    __builtin_amdgcn_s_barrier();
    asm volatile("" ::: "memory");

    const bfu* KsC = &Ks[cur][0];
    const bfu* VsC = &Vs[cur][0];
    const bool doA = (kt <= ktmA);

    // S^T[key][q] = K * Q^T  (kf shared by both q-tiles)
    floatx4 stA[8], stB[8];
    __builtin_amdgcn_s_setprio(1);
    if (doA) {
#pragma unroll
      for (int kk = 0; kk < 2; ++kk)
#pragma unroll
        for (int mk = 0; mk < 8; ++mk) {
          const short8 kf = *(const short8*)&KsC[(mk * 16 + c) * 64 + (((kk * 4 + g) ^ c7) << 3)];
          if (kk == 0) {
            stA[mk] = __builtin_amdgcn_mfma_f32_16x16x32_bf16(kf, bqA[0], z4, 0, 0, 0);
            stB[mk] = __builtin_amdgcn_mfma_f32_16x16x32_bf16(kf, bqB[0], z4, 0, 0, 0);
          } else {
            stA[mk] = __builtin_amdgcn_mfma_f32_16x16x32_bf16(kf, bqA[1], stA[mk], 0, 0, 0);
            stB[mk] = __builtin_amdgcn_mfma_f32_16x16x32_bf16(kf, bqB[1], stB[mk], 0, 0, 0);
          }
        }
    } else {
#pragma unroll
      for (int kk = 0; kk < 2; ++kk)
#pragma unroll
        for (int mk = 0; mk < 8; ++mk) {
          const short8 kf = *(const short8*)&KsC[(mk * 16 + c) * 64 + (((kk * 4 + g) ^ c7) << 3)];
          stB[mk] = __builtin_amdgcn_mfma_f32_16x16x32_bf16(kf, bqB[kk],
                                                            kk ? stB[mk] : z4, 0, 0, 0);
        }
    }
    __builtin_amdgcn_s_setprio(0);

    short4v paA[8], paB[8];
    if (doA) smax(stA, miA, liA, accA, paA, qwA, kt == ktmA, kt);
    smax(stB, miB, liB, accB, paB, qwB, kt == ktm, kt);

    // O += P * V via 16x16x16 (P in regs; vf shared by both q-tiles)
    __builtin_amdgcn_s_setprio(1);
    if (doA) {
#pragma unroll
      for (int mk = 0; mk < 8; ++mk)
#pragma unroll
        for (int nd = 0; nd < 4; ++nd) {
          const short4v vf = *(const short4v*)&VsC[(nd * 16 + c) * 128 +
              ((((mk << 1) + (g >> 1)) ^ c) << 3) + ((g & 1) << 2)];
          accA[nd] = __builtin_amdgcn_mfma_f32_16x16x16bf16_1k(paA[mk], vf, accA[nd], 0, 0, 0);
          accB[nd] = __builtin_amdgcn_mfma_f32_16x16x16bf16_1k(paB[mk], vf, accB[nd], 0, 0, 0);
        }
    } else {
#pragma unroll
      for (int mk = 0; mk < 8; ++mk)
#pragma unroll
        for (int nd = 0; nd < 4; ++nd) {
          const short4v vf = *(const short4v*)&VsC[(nd * 16 + c) * 128 +
              ((((mk << 1) + (g >> 1)) ^ c) << 3) + ((g & 1) << 2)];
          accB[nd] = __builtin_amdgcn_mfma_f32_16x16x16bf16_1k(paB[mk], vf, accB[nd], 0, 0, 0);
        }
    }
    __builtin_amdgcn_s_setprio(0);

    asm volatile("" ::: "memory");
    __builtin_amdgcn_s_barrier();     // all reads of buf[cur] done -> next
    asm volatile("" ::: "memory");    //   iter may overwrite it
  }

  // epilogue: O / l
  auto epi = [&](floatx4* acc, float li, int qw) {
#pragma unroll
    for (int r = 0; r < 4; ++r) {
      const float inv = 1.0f / __shfl(li, (lane & 48) | (g * 4 + r));
#pragma unroll
      for (int nd = 0; nd < 4; ++nd)
        obuf[(size_t)(b * Tsz + qw + g * 4 + r) * Dsz + h * 64 + nd * 16 + c] =
            f2bf(acc[nd][r] * inv);
    }
  };
  epi(accA, liA, qwA);
  epi(accB, liB, qwB);
}

extern "C" void kernel_launch(void* const* d_in, const int* in_sizes, int n_in,
                              void* d_out, int out_size, void* d_ws, size_t ws_size,
                              hipStream_t stream) {
  const float* x  = (const float*)d_in[0];
  const float* Wq = (const float*)d_in[1];
  const float* Wk = (const float*)d_in[2];
  const float* Wv = (const float*)d_in[3];
  const float* Wo = (const float*)d_in[4];
  float* out = (float*)d_out;

  // workspace (bf16 elems): wt 4x1M | qkv 3x4M (Q,K natural; slot 2 = VT) | obuf 4M = 40 MiB
  bfu* wt   = (bfu*)d_ws;
  bfu* qkv  = wt  + (size_t)4 * Dsz * Dsz;
  bfu* obuf = qkv + (size_t)3 * Msz * Dsz;

  transpose_w<<<dim3(32, 32, 4), dim3(32, 8), 0, stream>>>(Wq, Wk, Wv, Wo, wt);
  // QKV projections, x converted in-GEMM; Q scale folded into Wq; V -> VT (z==2)
  gemm128<false, true, 128><<<dim3(Dsz / 128, Msz / 128, 3), dim3(256), 0, stream>>>(
      (const void*)x, wt, (void*)qkv, Dsz, Dsz, (size_t)Dsz * Dsz, (size_t)Msz * Dsz);
  attn_kernel<<<dim3(16, Bsz * NHsz), dim3(256), 0, stream>>>(qkv, obuf);
  // output projection -> fp32 d_out (128x64 tiles: 512 blocks = 2/CU)
  gemm128<true, false, 64><<<dim3(Dsz / 64, Msz / 128, 1), dim3(256), 0, stream>>>(
      (const void*)obuf, wt + (size_t)3 * Dsz * Dsz, (void*)out, Dsz, Dsz,
      (size_t)0, (size_t)0);
}

// Round 3
// 199.311 us; speedup vs baseline: 1.0438x; 1.0438x over previous
//
#include <hip/hip_runtime.h>
#include <hip/hip_bf16.h>
#include <string.h>

#define Bsz 2
#define Tsz 2048
#define Dsz 1024
#define NHsz 16
#define Msz (Bsz*Tsz)  // 4096 rows total

typedef unsigned short bfu;  // bf16 bit pattern
typedef __attribute__((ext_vector_type(8))) short short8;   // MFMA A/B frag: 8 bf16
typedef __attribute__((ext_vector_type(4))) short short4v;
typedef __attribute__((ext_vector_type(4))) float floatx4;  // MFMA C/D frag

__device__ __forceinline__ bfu f2bf(float f) {
  unsigned int u = __builtin_bit_cast(unsigned int, f);
  u += 0x7fffu + ((u >> 16) & 1u);
  return (bfu)(u >> 16);
}

__device__ __forceinline__ float fexp2(float x) {
#if __has_builtin(__builtin_amdgcn_exp2f)
  return __builtin_amdgcn_exp2f(x);   // raw v_exp_f32 (no libm range fixup)
#else
  return exp2f(x);
#endif
}

__device__ __forceinline__ short4v pack4bf(float a, float b, float c_, float d) {
  // v_cvt_pk_bf16_f32: 2 ops for 4 values
  __hip_bfloat162 h01 = __float22bfloat162_rn(make_float2(a, b));
  __hip_bfloat162 h23 = __float22bfloat162_rn(make_float2(c_, d));
  uint2 uu;
  memcpy(&uu.x, &h01, 4);
  memcpy(&uu.y, &h23, 4);
  return __builtin_bit_cast(short4v, uu);
}

__device__ __forceinline__ short8 pack8bf(float4 a, float4 b) {
  __hip_bfloat162 h0 = __float22bfloat162_rn(make_float2(a.x, a.y));
  __hip_bfloat162 h1 = __float22bfloat162_rn(make_float2(a.z, a.w));
  __hip_bfloat162 h2 = __float22bfloat162_rn(make_float2(b.x, b.y));
  __hip_bfloat162 h3 = __float22bfloat162_rn(make_float2(b.z, b.w));
  uint4 u;
  memcpy(&u.x, &h0, 4); memcpy(&u.y, &h1, 4);
  memcpy(&u.z, &h2, 4); memcpy(&u.w, &h3, 4);
  return __builtin_bit_cast(short8, u);
}

__device__ __forceinline__ void async16(const void* g, void* l) {
  void* gnc = (void*)g;
  __builtin_amdgcn_global_load_lds((__attribute__((address_space(1))) void*)gnc,
                                   (__attribute__((address_space(3))) void*)l,
                                   16, 0, 0);
}

// ---------------- W (KxN fp32) -> WT (NxK bf16), z = 4 weights ----------------
// z==0 (Wq) pre-scaled by log2e/sqrt(DH) so the GEMM epilogue needs no scale.
__global__ __launch_bounds__(256) void transpose_w(const float* __restrict__ W0, const float* __restrict__ W1,
                                                   const float* __restrict__ W2, const float* __restrict__ W3,
                                                   bfu* __restrict__ wt) {
  __shared__ float tile[32][33];
  const float* W = blockIdx.z == 0 ? W0 : blockIdx.z == 1 ? W1 : blockIdx.z == 2 ? W2 : W3;
  const float s = (blockIdx.z == 0) ? 0.18033688011112042f : 1.0f;  // 0.125*log2(e)
  bfu* WT = wt + (size_t)blockIdx.z * Dsz * Dsz;
  int tx = threadIdx.x, ty = threadIdx.y;           // 32 x 8
  int kb = blockIdx.y * 32, nb = blockIdx.x * 32;
#pragma unroll
  for (int i = 0; i < 4; ++i)
    tile[ty + i*8][tx] = W[(size_t)(kb + ty + i*8) * Dsz + nb + tx];
  __syncthreads();
#pragma unroll
  for (int i = 0; i < 4; ++i)
    WT[(size_t)(nb + ty + i*8) * Dsz + kb + tx] = f2bf(tile[tx][ty + i*8] * s);
}

// ---------------- 128xNT bf16 MFMA GEMM: C = A(MxK) * BT(NxK)^T ----------------
// AF32: A fp32, converted in-regs (software-pipelined).
// z==2 (NT=128, bf16 out): V written transposed VT[b][h][d][t] via LDS-coalesced epilogue.
template <bool F32OUT, bool AF32, int NT>
__global__ __launch_bounds__(256) void gemm128(const void* __restrict__ Ain, const bfu* __restrict__ Bt0,
                                               void* __restrict__ C0, int K, int N,
                                               size_t strideB, size_t strideC) {
  constexpr int NJ = NT / 32;                       // n-frags per wave
  const int tid = threadIdx.x, wave = tid >> 6, lane = tid & 63;
  const int g = lane >> 4, c = lane & 15;
  const int m0 = blockIdx.y * 128, n0 = blockIdx.x * NT;
  const bfu* Bt = Bt0 + strideB * blockIdx.z;
  __shared__ bfu smem[4096 + NT * 32];              // As | Bs (also VT-transpose buf)
  bfu* As = smem;
  bfu* Bs = smem + 4096;
  floatx4 acc[4][NJ] = {};
  const int srow = lane >> 2, scol = (lane & 3) * 8;
  const bfu* gB = Bt + (size_t)(n0 + srow) * K + scol;
  const int wm = (wave >> 1) * 64, wn = (wave & 1) * (NT / 2);

  short8 areg[2];
  if (AF32) {   // preload k0=0 A-chunks as fp32, convert in regs
#pragma unroll
    for (int cc = 0; cc < 2; ++cc) {
      const float* pa = (const float*)Ain +
          (size_t)(m0 + (wave*2 + cc)*16 + srow) * K + scol;
      areg[cc] = pack8bf(((const float4*)pa)[0], ((const float4*)pa)[1]);
    }
  }
  const bfu* gA = AF32 ? nullptr : (const bfu*)Ain + (size_t)(m0 + srow) * K + scol;

  for (int k0 = 0; k0 < K; k0 += 32) {
    __syncthreads();               // prior reads done before overwrite
#pragma unroll
    for (int cc = 0; cc < 2; ++cc) {
      const int chunk = wave * 2 + cc;
      if (AF32) *(short8*)&As[chunk * 512 + lane * 8] = areg[cc];
      else      async16(gA + (size_t)chunk * 16 * K + k0, &As[chunk * 512]);
    }
#pragma unroll
    for (int cc = 0; cc < NT/64; ++cc) {
      const int chunk = wave * (NT/64) + cc;
      async16(gB + (size_t)chunk * 16 * K + k0, &Bs[chunk * 512]);
    }
    __syncthreads();
    if (AF32 && k0 + 32 < K) {     // prefetch next A slab (overlaps with MFMA below)
#pragma unroll
      for (int cc = 0; cc < 2; ++cc) {
        const float* pa = (const float*)Ain +
            (size_t)(m0 + (wave*2 + cc)*16 + srow) * K + (k0 + 32) + scol;
        areg[cc] = pack8bf(((const float4*)pa)[0], ((const float4*)pa)[1]);
      }
    }
    short8 afr[4], bfr[NJ];
#pragma unroll
    for (int t = 0; t < 4; ++t) afr[t] = *(const short8*)&As[(wm + t*16 + c) * 32 + g * 8];
#pragma unroll
    for (int t = 0; t < NJ; ++t) bfr[t] = *(const short8*)&Bs[(wn + t*16 + c) * 32 + g * 8];
#pragma unroll
    for (int i = 0; i < 4; ++i)
#pragma unroll
      for (int j = 0; j < NJ; ++j)
        acc[i][j] = __builtin_amdgcn_mfma_f32_16x16x32_bf16(afr[i], bfr[j], acc[i][j], 0, 0, 0);
  }

  const bool vtrans = (!F32OUT) && (NT == 128) && (blockIdx.z == 2);
  if (vtrans) {
    // LDS-coalesced transpose: 2 passes of 64 n-cols (= one head each) x 128 m.
    bfu* vtp = (bfu*)C0 + (size_t)2 * strideC;
#pragma unroll
    for (int p = 0; p < 2; ++p) {
      __syncthreads();             // As/Bs reads (or prior pass stores) complete
      if ((wave & 1) == p) {       // waves holding n-cols [p*64, p*64+64)
#pragma unroll
        for (int i = 0; i < 4; ++i)
#pragma unroll
          for (int j = 0; j < NJ; ++j) {
            const int nl = j*16 + c;                      // 0..63 within pass
            const int mg = ((wm + i*16) >> 3) + (g >> 1); // m-granule of 8
            const int phys = nl * 128 + ((mg ^ (nl & 15)) << 3) + ((g & 1) << 2);
            *(short4v*)&smem[phys] = pack4bf(acc[i][j][0], acc[i][j][1],
                                             acc[i][j][2], acc[i][j][3]);
          }
      }
      __syncthreads();
      const int h_ = (n0 + p * 64) >> 6;
      bfu* dst = vtp + ((size_t)((m0 >> 11) * 16 + h_) * 64) * Tsz + (m0 & 2047);
#pragma unroll
      for (int s = 0; s < 4; ++s) {
        const int nl = s * 16 + (tid >> 4);
        const int me = (tid & 15) << 3;
        const int phys = nl * 128 + (((me >> 3) ^ (nl & 15)) << 3);
        *(short8*)&dst[(size_t)nl * Tsz + me] = *(const short8*)&smem[phys];
      }
    }
    return;
  }

#pragma unroll
  for (int i = 0; i < 4; ++i) {
#pragma unroll
    for (int j = 0; j < NJ; ++j) {
      const int m = m0 + wm + i*16 + g*4;
      const int n = n0 + wn + j*16 + c;
#pragma unroll
      for (int r = 0; r < 4; ++r) {
        float v = acc[i][j][r];
        if (F32OUT) ((float*)C0)[(size_t)(m + r) * N + n] = v;
        else        ((bfu*)C0)[strideC * blockIdx.z + (size_t)(m + r) * N + n] = f2bf(v);
      }
    }
  }
}

// ---------------- causal flash attention (S^T formulation, v3) ----------------
// Q,K natural [b*T+t][h*64+d]; V transposed at qkv+2*M*D as VT[b][h][d][t].
// Q pre-scaled by log2e/sqrt(DH) (folded into Wq).
// v3 structure (occupancy-first):
//  * UNPAIRED: one 64-row q-tile j per block, 64-key K/V tiles, kt = 0..j.
//    Grid 1024 blocks x 256 thr; LDS 32KB; __launch_bounds__(256,4) ->
//    4 blocks/CU = 16 waves/CU = 4 waves/SIMD (v2 was stuck at 2/SIMD).
//  * balanced remap: each XCD owns 4 heads (K/V 2MB in its L2); each CU gets
//    j-mix {t, 31-t, t+16, 15-t} -> per-CU tile count = 66 = constant.
//  * K/V double-buffered, counted s_waitcnt vmcnt(4), raw s_barrier.
//  * PV via v_mfma_f32_16x16x16bf16_1k: P stays in registers (A-frag layout
//    == QK^T C-frag layout).  * defer-max (T13).  * raw v_exp_f32.
__global__ __launch_bounds__(256, 4) void attn_kernel(const bfu* __restrict__ qkv,
                                                      bfu* __restrict__ obuf) {
  const int tid = threadIdx.x, wave = tid >> 6, lane = tid & 63;
  const int g = (lane >> 4) & 3, c = lane & 15, c7 = c & 7;

  // remap: flat -> xcd (bits 2:0), idx = flat>>3; s = head-slot, t ~ CU slot
  const int flat = (int)blockIdx.y * 32 + (int)blockIdx.x;
  const int xcd = flat & 7, idx = flat >> 3;
  const int s = idx >> 5, t = idx & 31;
  const int tt = (s & 2) ? ((t + 16) & 31) : t;
  const int j  = (s & 1) ? (31 - tt) : tt;      // q-tile index 0..31
  const int bh = xcd * 4 + s;
  const int b = bh >> 4, h = bh & 15;

  const size_t hbq = (size_t)b * Tsz * Dsz + h * 64;
  const bfu* Qp = qkv + hbq;
  const bfu* Kp = qkv + (size_t)Msz * Dsz + hbq;
  const bfu* Vt = qkv + (size_t)2 * Msz * Dsz + (size_t)bh * 64 * Tsz;

  __shared__ bfu Ks[2][64 * 64];      // [key][d], d-octets XOR (key&7)
  __shared__ bfu Vs[2][64 * 64];      // [d][key], key-octets XOR (d&7)

  const int qw = j * 64 + wave * 16;

  short8 bq[2];                        // Q B-frags: n=q=qw+c, k=d
#pragma unroll
  for (int kk = 0; kk < 2; ++kk)
    bq[kk] = *(const short8*)(Qp + (size_t)(qw + c) * Dsz + kk * 32 + g * 8);

  // staging: chunk ch = wave*2+cc covers 8 rows; 8 lanes/row, 16B (=1 octet) each;
  // global octet pre-swizzled by row&7 so linear LDS + swizzled reads match.
  const int srow8 = lane >> 3;                       // row within chunk (0..7)
  const int soff = ((lane & 7) ^ srow8) << 3;        // swizzled octet offset
  const bfu* kpp[2]; const bfu* vpp[2];
#pragma unroll
  for (int cc = 0; cc < 2; ++cc) {
    const int ch = wave * 2 + cc;
    kpp[cc] = Kp + (size_t)(ch * 8 + srow8) * Dsz + soff;   // K rows (keys)
    vpp[cc] = Vt + (size_t)(ch * 8 + srow8) * Tsz + soff;   // V rows (d)
  }

  floatx4 acc[4] = {};                 // O: rows q=4g+r, cols d=nd*16+c
  float mi = -3.0e38f, li = 0.0f;      // state for q = qw + c (replicated over g)
  const floatx4 z4 = {0.0f, 0.0f, 0.0f, 0.0f};

  // prologue: stage kt=0 into buf 0
#pragma unroll
  for (int cc = 0; cc < 2; ++cc) {
    const int ch = wave * 2 + cc;
    async16(kpp[cc], &Ks[0][ch * 512]);
    async16(vpp[cc], &Vs[0][ch * 512]);
    kpp[cc] += (size_t)64 * Dsz;
    vpp[cc] += 64;
  }

  for (int kt = 0; kt <= j; ++kt) {
    const int cur = kt & 1;
    if (kt < j) {                      // prefetch kt+1 into other buffer
#pragma unroll
      for (int cc = 0; cc < 2; ++cc) {
        const int ch = wave * 2 + cc;
        async16(kpp[cc], &Ks[cur ^ 1][ch * 512]);
        async16(vpp[cc], &Vs[cur ^ 1][ch * 512]);
        kpp[cc] += (size_t)64 * Dsz;
        vpp[cc] += 64;
      }
      asm volatile("s_waitcnt vmcnt(4)" ::: "memory");  // cur's 4 landed
    } else {
      asm volatile("s_waitcnt vmcnt(0)" ::: "memory");
    }
    __builtin_amdgcn_s_barrier();
    asm volatile("" ::: "memory");

    const bfu* KsC = &Ks[cur][0];
    const bfu* VsC = &Vs[cur][0];

    // S^T[key][q] = K * Q^T
    floatx4 st[4];
    __builtin_amdgcn_s_setprio(1);
#pragma unroll
    for (int mk = 0; mk < 4; ++mk) {
      const short8 kf = *(const short8*)&KsC[(mk * 16 + c) * 64 + ((g ^ c7) << 3)];
      st[mk] = __builtin_amdgcn_mfma_f32_16x16x32_bf16(kf, bq[0], z4, 0, 0, 0);
    }
#pragma unroll
    for (int mk = 0; mk < 4; ++mk) {
      const short8 kf = *(const short8*)&KsC[(mk * 16 + c) * 64 + (((4 + g) ^ c7) << 3)];
      st[mk] = __builtin_amdgcn_mfma_f32_16x16x32_bf16(kf, bq[1], st[mk], 0, 0, 0);
    }
    __builtin_amdgcn_s_setprio(0);

    if (kt == j) {                     // causal mask (diagonal tile only)
#pragma unroll
      for (int mk = 0; mk < 4; ++mk) {
        const int keyb = kt * 64 + mk * 16 + g * 4;
#pragma unroll
        for (int r = 0; r < 4; ++r)
          if (keyb + r > qw + c) st[mk][r] = -1.0e38f;
      }
    }

    // online softmax over this tile's 64 keys (per lane: q = qw+c)
    float mloc = -3.0e38f;
#pragma unroll
    for (int mk = 0; mk < 4; ++mk)
      mloc = fmaxf(mloc, fmaxf(fmaxf(st[mk][0], st[mk][1]),
                               fmaxf(st[mk][2], st[mk][3])));
    mloc = fmaxf(mloc, __shfl_xor(mloc, 16));
    mloc = fmaxf(mloc, __shfl_xor(mloc, 32));
    const float mcand = fmaxf(mi, mloc);
    const bool resc = !__all(mcand - mi <= 8.0f);   // defer-max (T13)
    const float mnew = resc ? mcand : mi;
    float sum = 0.0f;
    short4v pa[4];                     // P as K=16 A-frags, in regs
#pragma unroll
    for (int mk = 0; mk < 4; ++mk) {
      const float p0 = fexp2(st[mk][0] - mnew);
      const float p1 = fexp2(st[mk][1] - mnew);
      const float p2 = fexp2(st[mk][2] - mnew);
      const float p3 = fexp2(st[mk][3] - mnew);
      sum += (p0 + p1) + (p2 + p3);
      pa[mk] = pack4bf(p0, p1, p2, p3);
    }
    sum += __shfl_xor(sum, 16);
    sum += __shfl_xor(sum, 32);
    if (resc) {
      const float alpha = fexp2(mi - mnew);
      li = li * alpha + sum;
      mi = mnew;
      float al[4];
#pragma unroll
      for (int r = 0; r < 4; ++r) al[r] = __shfl(alpha, (lane & 48) | (g * 4 + r));
#pragma unroll
      for (int nd = 0; nd < 4; ++nd)
#pragma unroll
        for (int r = 0; r < 4; ++r) acc[nd][r] *= al[r];
    } else {
      li += sum;
    }

    // O += P * V via 16x16x16 (P in regs)
    __builtin_amdgcn_s_setprio(1);
#pragma unroll
    for (int mk = 0; mk < 4; ++mk)
#pragma unroll
      for (int nd = 0; nd < 4; ++nd) {
        const short4v vf = *(const short4v*)&VsC[(nd * 16 + c) * 64 +
            ((((mk << 1) + (g >> 1)) ^ c7) << 3) + ((g & 1) << 2)];
        acc[nd] = __builtin_amdgcn_mfma_f32_16x16x16bf16_1k(pa[mk], vf, acc[nd], 0, 0, 0);
      }
    __builtin_amdgcn_s_setprio(0);

    asm volatile("" ::: "memory");
    __builtin_amdgcn_s_barrier();     // all reads of buf[cur] done -> next
    asm volatile("" ::: "memory");    //   iter may overwrite it
  }

  // epilogue: O / l
#pragma unroll
  for (int r = 0; r < 4; ++r) {
    const float inv = 1.0f / __shfl(li, (lane & 48) | (g * 4 + r));
#pragma unroll
    for (int nd = 0; nd < 4; ++nd)
      obuf[(size_t)(b * Tsz + qw + g * 4 + r) * Dsz + h * 64 + nd * 16 + c] =
          f2bf(acc[nd][r] * inv);
  }
}

extern "C" void kernel_launch(void* const* d_in, const int* in_sizes, int n_in,
                              void* d_out, int out_size, void* d_ws, size_t ws_size,
                              hipStream_t stream) {
  const float* x  = (const float*)d_in[0];
  const float* Wq = (const float*)d_in[1];
  const float* Wk = (const float*)d_in[2];
  const float* Wv = (const float*)d_in[3];
  const float* Wo = (const float*)d_in[4];
  float* out = (float*)d_out;

  // workspace (bf16 elems): wt 4x1M | qkv 3x4M (Q,K natural; slot 2 = VT) | obuf 4M = 40 MiB
  bfu* wt   = (bfu*)d_ws;
  bfu* qkv  = wt  + (size_t)4 * Dsz * Dsz;
  bfu* obuf = qkv + (size_t)3 * Msz * Dsz;

  transpose_w<<<dim3(32, 32, 4), dim3(32, 8), 0, stream>>>(Wq, Wk, Wv, Wo, wt);
  // QKV projections, x converted in-GEMM; Q scale folded into Wq; V -> VT (z==2)
  gemm128<false, true, 128><<<dim3(Dsz / 128, Msz / 128, 3), dim3(256), 0, stream>>>(
      (const void*)x, wt, (void*)qkv, Dsz, Dsz, (size_t)Dsz * Dsz, (size_t)Msz * Dsz);
  attn_kernel<<<dim3(32, 32), dim3(256), 0, stream>>>(qkv, obuf);
  // output projection -> fp32 d_out (128x64 tiles: 512 blocks = 2/CU)
  gemm128<true, false, 64><<<dim3(Dsz / 64, Msz / 128, 1), dim3(256), 0, stream>>>(
      (const void*)obuf, wt + (size_t)3 * Dsz * Dsz, (void*)out, Dsz, Dsz,
      (size_t)0, (size_t)0);
}

// Round 4
// 193.191 us; speedup vs baseline: 1.0769x; 1.0317x over previous
//
#include <hip/hip_runtime.h>
#include <hip/hip_bf16.h>
#include <string.h>

#define Bsz 2
#define Tsz 2048
#define Dsz 1024
#define NHsz 16
#define Msz (Bsz*Tsz)  // 4096 rows total

typedef unsigned short bfu;  // bf16 bit pattern
typedef __attribute__((ext_vector_type(8))) short short8;   // MFMA A/B frag: 8 bf16
typedef __attribute__((ext_vector_type(4))) short short4v;
typedef __attribute__((ext_vector_type(4))) float floatx4;  // MFMA C/D frag

__device__ __forceinline__ bfu f2bf(float f) {
  unsigned int u = __builtin_bit_cast(unsigned int, f);
  u += 0x7fffu + ((u >> 16) & 1u);
  return (bfu)(u >> 16);
}

__device__ __forceinline__ float fexp2(float x) {
#if __has_builtin(__builtin_amdgcn_exp2f)
  return __builtin_amdgcn_exp2f(x);   // raw v_exp_f32 (no libm range fixup)
#else
  return exp2f(x);
#endif
}

__device__ __forceinline__ short4v pack4bf(float a, float b, float c_, float d) {
  // v_cvt_pk_bf16_f32: 2 ops for 4 values
  __hip_bfloat162 h01 = __float22bfloat162_rn(make_float2(a, b));
  __hip_bfloat162 h23 = __float22bfloat162_rn(make_float2(c_, d));
  uint2 uu;
  memcpy(&uu.x, &h01, 4);
  memcpy(&uu.y, &h23, 4);
  return __builtin_bit_cast(short4v, uu);
}

__device__ __forceinline__ short8 pack8bf(float4 a, float4 b) {
  __hip_bfloat162 h0 = __float22bfloat162_rn(make_float2(a.x, a.y));
  __hip_bfloat162 h1 = __float22bfloat162_rn(make_float2(a.z, a.w));
  __hip_bfloat162 h2 = __float22bfloat162_rn(make_float2(b.x, b.y));
  __hip_bfloat162 h3 = __float22bfloat162_rn(make_float2(b.z, b.w));
  uint4 u;
  memcpy(&u.x, &h0, 4); memcpy(&u.y, &h1, 4);
  memcpy(&u.z, &h2, 4); memcpy(&u.w, &h3, 4);
  return __builtin_bit_cast(short8, u);
}

__device__ __forceinline__ void async16(const void* g, void* l) {
  void* gnc = (void*)g;
  __builtin_amdgcn_global_load_lds((__attribute__((address_space(1))) void*)gnc,
                                   (__attribute__((address_space(3))) void*)l,
                                   16, 0, 0);
}

// ---------------- W (KxN fp32) -> WT (NxK bf16), z = 4 weights ----------------
// z==0 (Wq) pre-scaled by log2e/sqrt(DH) so the GEMM epilogue needs no scale.
__global__ __launch_bounds__(256) void transpose_w(const float* __restrict__ W0, const float* __restrict__ W1,
                                                   const float* __restrict__ W2, const float* __restrict__ W3,
                                                   bfu* __restrict__ wt) {
  __shared__ float tile[32][33];
  const float* W = blockIdx.z == 0 ? W0 : blockIdx.z == 1 ? W1 : blockIdx.z == 2 ? W2 : W3;
  const float s = (blockIdx.z == 0) ? 0.18033688011112042f : 1.0f;  // 0.125*log2(e)
  bfu* WT = wt + (size_t)blockIdx.z * Dsz * Dsz;
  int tx = threadIdx.x, ty = threadIdx.y;           // 32 x 8
  int kb = blockIdx.y * 32, nb = blockIdx.x * 32;
#pragma unroll
  for (int i = 0; i < 4; ++i)
    tile[ty + i*8][tx] = W[(size_t)(kb + ty + i*8) * Dsz + nb + tx];
  __syncthreads();
#pragma unroll
  for (int i = 0; i < 4; ++i)
    WT[(size_t)(nb + ty + i*8) * Dsz + kb + tx] = f2bf(tile[tx][ty + i*8] * s);
}

// ---------------- 128xNT bf16 MFMA GEMM: C = A(MxK) * BT(NxK)^T ----------------
// AF32: A fp32, converted in-regs (software-pipelined).
// z==2 (NT=128, bf16 out): V written transposed VT[b][h][d][t] via LDS-coalesced epilogue.
template <bool F32OUT, bool AF32, int NT>
__global__ __launch_bounds__(256) void gemm128(const void* __restrict__ Ain, const bfu* __restrict__ Bt0,
                                               void* __restrict__ C0, int K, int N,
                                               size_t strideB, size_t strideC) {
  constexpr int NJ = NT / 32;                       // n-frags per wave
  const int tid = threadIdx.x, wave = tid >> 6, lane = tid & 63;
  const int g = lane >> 4, c = lane & 15;
  const int m0 = blockIdx.y * 128, n0 = blockIdx.x * NT;
  const bfu* Bt = Bt0 + strideB * blockIdx.z;
  __shared__ bfu smem[4096 + NT * 32];              // As | Bs (also VT-transpose buf)
  bfu* As = smem;
  bfu* Bs = smem + 4096;
  floatx4 acc[4][NJ] = {};
  const int srow = lane >> 2, scol = (lane & 3) * 8;
  const bfu* gB = Bt + (size_t)(n0 + srow) * K + scol;
  const int wm = (wave >> 1) * 64, wn = (wave & 1) * (NT / 2);

  short8 areg[2];
  if (AF32) {   // preload k0=0 A-chunks as fp32, convert in regs
#pragma unroll
    for (int cc = 0; cc < 2; ++cc) {
      const float* pa = (const float*)Ain +
          (size_t)(m0 + (wave*2 + cc)*16 + srow) * K + scol;
      areg[cc] = pack8bf(((const float4*)pa)[0], ((const float4*)pa)[1]);
    }
  }
  const bfu* gA = AF32 ? nullptr : (const bfu*)Ain + (size_t)(m0 + srow) * K + scol;

  for (int k0 = 0; k0 < K; k0 += 32) {
    __syncthreads();               // prior reads done before overwrite
#pragma unroll
    for (int cc = 0; cc < 2; ++cc) {
      const int chunk = wave * 2 + cc;
      if (AF32) *(short8*)&As[chunk * 512 + lane * 8] = areg[cc];
      else      async16(gA + (size_t)chunk * 16 * K + k0, &As[chunk * 512]);
    }
#pragma unroll
    for (int cc = 0; cc < NT/64; ++cc) {
      const int chunk = wave * (NT/64) + cc;
      async16(gB + (size_t)chunk * 16 * K + k0, &Bs[chunk * 512]);
    }
    __syncthreads();
    if (AF32 && k0 + 32 < K) {     // prefetch next A slab (overlaps with MFMA below)
#pragma unroll
      for (int cc = 0; cc < 2; ++cc) {
        const float* pa = (const float*)Ain +
            (size_t)(m0 + (wave*2 + cc)*16 + srow) * K + (k0 + 32) + scol;
        areg[cc] = pack8bf(((const float4*)pa)[0], ((const float4*)pa)[1]);
      }
    }
    short8 afr[4], bfr[NJ];
#pragma unroll
    for (int t = 0; t < 4; ++t) afr[t] = *(const short8*)&As[(wm + t*16 + c) * 32 + g * 8];
#pragma unroll
    for (int t = 0; t < NJ; ++t) bfr[t] = *(const short8*)&Bs[(wn + t*16 + c) * 32 + g * 8];
#pragma unroll
    for (int i = 0; i < 4; ++i)
#pragma unroll
      for (int j = 0; j < NJ; ++j)
        acc[i][j] = __builtin_amdgcn_mfma_f32_16x16x32_bf16(afr[i], bfr[j], acc[i][j], 0, 0, 0);
  }

  const bool vtrans = (!F32OUT) && (NT == 128) && (blockIdx.z == 2);
  if (vtrans) {
    // LDS-coalesced transpose: 2 passes of 64 n-cols (= one head each) x 128 m.
    bfu* vtp = (bfu*)C0 + (size_t)2 * strideC;
#pragma unroll
    for (int p = 0; p < 2; ++p) {
      __syncthreads();             // As/Bs reads (or prior pass stores) complete
      if ((wave & 1) == p) {       // waves holding n-cols [p*64, p*64+64)
#pragma unroll
        for (int i = 0; i < 4; ++i)
#pragma unroll
          for (int j = 0; j < NJ; ++j) {
            const int nl = j*16 + c;                      // 0..63 within pass
            const int mg = ((wm + i*16) >> 3) + (g >> 1); // m-granule of 8
            const int phys = nl * 128 + ((mg ^ (nl & 15)) << 3) + ((g & 1) << 2);
            *(short4v*)&smem[phys] = pack4bf(acc[i][j][0], acc[i][j][1],
                                             acc[i][j][2], acc[i][j][3]);
          }
      }
      __syncthreads();
      const int h_ = (n0 + p * 64) >> 6;
      bfu* dst = vtp + ((size_t)((m0 >> 11) * 16 + h_) * 64) * Tsz + (m0 & 2047);
#pragma unroll
      for (int s = 0; s < 4; ++s) {
        const int nl = s * 16 + (tid >> 4);
        const int me = (tid & 15) << 3;
        const int phys = nl * 128 + (((me >> 3) ^ (nl & 15)) << 3);
        *(short8*)&dst[(size_t)nl * Tsz + me] = *(const short8*)&smem[phys];
      }
    }
    return;
  }

#pragma unroll
  for (int i = 0; i < 4; ++i) {
#pragma unroll
    for (int j = 0; j < NJ; ++j) {
      const int m = m0 + wm + i*16 + g*4;
      const int n = n0 + wn + j*16 + c;
#pragma unroll
      for (int r = 0; r < 4; ++r) {
        float v = acc[i][j][r];
        if (F32OUT) ((float*)C0)[(size_t)(m + r) * N + n] = v;
        else        ((bfu*)C0)[strideC * blockIdx.z + (size_t)(m + r) * N + n] = f2bf(v);
      }
    }
  }
}

// ---------------- causal flash attention (S^T formulation, v4) ----------------
// Q,K natural [b*T+t][h*64+d]; V transposed at qkv+2*M*D as VT[b][h][d][t].
// Q pre-scaled by log2e/sqrt(DH) (folded into Wq).
// v4 structure (latency-first):
//  * EQUAL-LENGTH blocks: block = q-tile pair {j0, 31-j0} processed
//    SEQUENTIALLY -> every block = exactly 33 key-tiles. 512 blocks = 2/CU,
//    steady 8 waves/CU for the whole kernel (v3 decayed 16 -> ~4).
//  * NO cross-lane ops on the common softmax path: li kept as per-lane
//    PARTIAL (each lane sums only its own exp'd keys; g-replicas reduced
//    once at the end). Per tile: local max + __all(mloc<=mi+8) scalar test.
//    Full max-reduce + rescale only on the rare resc event.
//  * K/V double-buffered, counted s_waitcnt vmcnt(4), raw s_barrier.
//  * PV via v_mfma_f32_16x16x16bf16_1k: P stays in registers (A-frag layout
//    == QK^T C-frag layout).  * XCD owns 4 heads (K/V 2MB in its L2).
__global__ __launch_bounds__(256, 2) void attn_kernel(const bfu* __restrict__ qkv,
                                                      bfu* __restrict__ obuf) {
  const int tid = threadIdx.x, wave = tid >> 6, lane = tid & 63;
  const int g = (lane >> 4) & 3, c = lane & 15, c7 = c & 7;

  // remap: flat(0..511) -> xcd (bits 2:0), head-slot (bits 4:3), pair j0 (bits 8:5)
  const int flat = (int)blockIdx.y * 16 + (int)blockIdx.x;
  const int xcd = flat & 7, r_ = flat >> 3;
  const int s = r_ & 3, j0 = r_ >> 2;           // j0 = 0..15
  const int bh = xcd * 4 + s;
  const int b = bh >> 4, h = bh & 15;

  const size_t hbq = (size_t)b * Tsz * Dsz + h * 64;
  const bfu* Qp = qkv + hbq;
  const bfu* Kp = qkv + (size_t)Msz * Dsz + hbq;
  const bfu* Vt = qkv + (size_t)2 * Msz * Dsz + (size_t)bh * 64 * Tsz;

  __shared__ bfu Ks[2][64 * 64];      // [key][d], d-octets XOR (key&7)
  __shared__ bfu Vs[2][64 * 64];      // [d][key], key-octets XOR (d&7)

  // staging geometry: chunk ch = wave*2+cc covers 8 rows; 8 lanes/row, 16B each;
  // global octet pre-swizzled by row&7 so linear LDS + swizzled reads match.
  const int srow8 = lane >> 3;                       // row within chunk (0..7)
  const int soff = ((lane & 7) ^ srow8) << 3;        // swizzled octet offset
  const floatx4 z4 = {0.0f, 0.0f, 0.0f, 0.0f};

  for (int hf = 0; hf < 2; ++hf) {
    const int j = hf ? (31 - j0) : j0;               // q-tile index 0..31
    const int qw = j * 64 + wave * 16;

    short8 bq[2];                      // Q B-frags: n=q=qw+c, k=d
#pragma unroll
    for (int kk = 0; kk < 2; ++kk)
      bq[kk] = *(const short8*)(Qp + (size_t)(qw + c) * Dsz + kk * 32 + g * 8);

    const bfu* kpp[2]; const bfu* vpp[2];
#pragma unroll
    for (int cc = 0; cc < 2; ++cc) {
      const int ch = wave * 2 + cc;
      kpp[cc] = Kp + (size_t)(ch * 8 + srow8) * Dsz + soff;   // K rows (keys)
      vpp[cc] = Vt + (size_t)(ch * 8 + srow8) * Tsz + soff;   // V rows (d)
    }

    floatx4 acc[4] = {};               // O: rows q=4g+r, cols d=nd*16+c
    float mi = -3.0e38f, li = 0.0f;    // li = PARTIAL sum (this lane's keys only)

    // prologue: stage kt=0 into buf 0 (safe: prior half's end barrier +
    // vmcnt(0) guarantee all reads/loads of both buffers are complete)
#pragma unroll
    for (int cc = 0; cc < 2; ++cc) {
      const int ch = wave * 2 + cc;
      async16(kpp[cc], &Ks[0][ch * 512]);
      async16(vpp[cc], &Vs[0][ch * 512]);
      kpp[cc] += (size_t)64 * Dsz;
      vpp[cc] += 64;
    }

    for (int kt = 0; kt <= j; ++kt) {
      const int cur = kt & 1;
      if (kt < j) {                    // prefetch kt+1 into other buffer
#pragma unroll
        for (int cc = 0; cc < 2; ++cc) {
          const int ch = wave * 2 + cc;
          async16(kpp[cc], &Ks[cur ^ 1][ch * 512]);
          async16(vpp[cc], &Vs[cur ^ 1][ch * 512]);
          kpp[cc] += (size_t)64 * Dsz;
          vpp[cc] += 64;
        }
        asm volatile("s_waitcnt vmcnt(4)" ::: "memory");  // cur's 4 landed
      } else {
        asm volatile("s_waitcnt vmcnt(0)" ::: "memory");
      }
      __builtin_amdgcn_s_barrier();
      asm volatile("" ::: "memory");

      const bfu* KsC = &Ks[cur][0];
      const bfu* VsC = &Vs[cur][0];

      // S^T[key][q] = K * Q^T
      floatx4 st[4];
      __builtin_amdgcn_s_setprio(1);
#pragma unroll
      for (int mk = 0; mk < 4; ++mk) {
        const short8 kf = *(const short8*)&KsC[(mk * 16 + c) * 64 + ((g ^ c7) << 3)];
        st[mk] = __builtin_amdgcn_mfma_f32_16x16x32_bf16(kf, bq[0], z4, 0, 0, 0);
      }
#pragma unroll
      for (int mk = 0; mk < 4; ++mk) {
        const short8 kf = *(const short8*)&KsC[(mk * 16 + c) * 64 + (((4 + g) ^ c7) << 3)];
        st[mk] = __builtin_amdgcn_mfma_f32_16x16x32_bf16(kf, bq[1], st[mk], 0, 0, 0);
      }
      __builtin_amdgcn_s_setprio(0);

      if (kt == j) {                   // causal mask (diagonal tile only)
#pragma unroll
        for (int mk = 0; mk < 4; ++mk) {
          const int keyb = kt * 64 + mk * 16 + g * 4;
#pragma unroll
          for (int r = 0; r < 4; ++r)
            if (keyb + r > qw + c) st[mk][r] = -1.0e38f;
        }
      }

      // online softmax, no cross-lane on common path (partial li)
      float mloc = -3.0e38f;
#pragma unroll
      for (int mk = 0; mk < 4; ++mk)
        mloc = fmaxf(mloc, fmaxf(fmaxf(st[mk][0], st[mk][1]),
                                 fmaxf(st[mk][2], st[mk][3])));
      const bool resc = !__all(mloc <= mi + 8.0f);  // defer-max (T13)
      if (resc) {                      // rare: full reduce + rescale
        float mr = fmaxf(mloc, __shfl_xor(mloc, 16));
        mr = fmaxf(mr, __shfl_xor(mr, 32));
        const float mnew = fmaxf(mi, mr);
        const float alpha = fexp2(mi - mnew);
        li *= alpha;
        mi = mnew;
        float al[4];
#pragma unroll
        for (int rr = 0; rr < 4; ++rr) al[rr] = __shfl(alpha, (lane & 48) | (g * 4 + rr));
#pragma unroll
        for (int nd = 0; nd < 4; ++nd)
#pragma unroll
          for (int rr = 0; rr < 4; ++rr) acc[nd][rr] *= al[rr];
      }
      short4v pa[4];                   // P as K=16 A-frags, in regs
#pragma unroll
      for (int mk = 0; mk < 4; ++mk) {
        const float p0 = fexp2(st[mk][0] - mi);
        const float p1 = fexp2(st[mk][1] - mi);
        const float p2 = fexp2(st[mk][2] - mi);
        const float p3 = fexp2(st[mk][3] - mi);
        li += (p0 + p1) + (p2 + p3);
        pa[mk] = pack4bf(p0, p1, p2, p3);
      }

      // O += P * V via 16x16x16 (P in regs)
      __builtin_amdgcn_s_setprio(1);
#pragma unroll
      for (int mk = 0; mk < 4; ++mk)
#pragma unroll
        for (int nd = 0; nd < 4; ++nd) {
          const short4v vf = *(const short4v*)&VsC[(nd * 16 + c) * 64 +
              ((((mk << 1) + (g >> 1)) ^ c7) << 3) + ((g & 1) << 2)];
          acc[nd] = __builtin_amdgcn_mfma_f32_16x16x16bf16_1k(pa[mk], vf, acc[nd], 0, 0, 0);
        }
      __builtin_amdgcn_s_setprio(0);

      asm volatile("" ::: "memory");
      __builtin_amdgcn_s_barrier();   // all reads of buf[cur] done -> next
      asm volatile("" ::: "memory");  //   iter may overwrite it
    }

    // reduce the 4 g-replica partial sums once, then epilogue: O / l
    float lt = li;
    lt += __shfl_xor(lt, 16);
    lt += __shfl_xor(lt, 32);
#pragma unroll
    for (int rr = 0; rr < 4; ++rr) {
      const float inv = 1.0f / __shfl(lt, (lane & 48) | (g * 4 + rr));
#pragma unroll
      for (int nd = 0; nd < 4; ++nd)
        obuf[(size_t)(b * Tsz + qw + g * 4 + rr) * Dsz + h * 64 + nd * 16 + c] =
            f2bf(acc[nd][rr] * inv);
    }
  }
}

extern "C" void kernel_launch(void* const* d_in, const int* in_sizes, int n_in,
                              void* d_out, int out_size, void* d_ws, size_t ws_size,
                              hipStream_t stream) {
  const float* x  = (const float*)d_in[0];
  const float* Wq = (const float*)d_in[1];
  const float* Wk = (const float*)d_in[2];
  const float* Wv = (const float*)d_in[3];
  const float* Wo = (const float*)d_in[4];
  float* out = (float*)d_out;

  // workspace (bf16 elems): wt 4x1M | qkv 3x4M (Q,K natural; slot 2 = VT) | obuf 4M = 40 MiB
  bfu* wt   = (bfu*)d_ws;
  bfu* qkv  = wt  + (size_t)4 * Dsz * Dsz;
  bfu* obuf = qkv + (size_t)3 * Msz * Dsz;

  transpose_w<<<dim3(32, 32, 4), dim3(32, 8), 0, stream>>>(Wq, Wk, Wv, Wo, wt);
  // QKV projections, x converted in-GEMM; Q scale folded into Wq; V -> VT (z==2)
  gemm128<false, true, 128><<<dim3(Dsz / 128, Msz / 128, 3), dim3(256), 0, stream>>>(
      (const void*)x, wt, (void*)qkv, Dsz, Dsz, (size_t)Dsz * Dsz, (size_t)Msz * Dsz);
  attn_kernel<<<dim3(16, 32), dim3(256), 0, stream>>>(qkv, obuf);
  // output projection -> fp32 d_out (128x64 tiles: 512 blocks = 2/CU)
  gemm128<true, false, 64><<<dim3(Dsz / 64, Msz / 128, 1), dim3(256), 0, stream>>>(
      (const void*)obuf, wt + (size_t)3 * Dsz * Dsz, (void*)out, Dsz, Dsz,
      (size_t)0, (size_t)0);
}